// Round 5
// baseline (101.273 us; speedup 1.0000x reference)
//
#include <hip/hip_runtime.h>
#include <hip/hip_bf16.h>

#define B_ROWS 4096
#define N_ROWS 8192
#define D 128
#define SCALE 2.885390081777927f   // (1/temperature) * log2(e)
#define LN2 0.6931471805599453f

#define RB 256             // rows per block = 4 waves x 64 rows
#define CSPLIT 512         // columns swept per block
#define NSTRIPE (N_ROWS / CSPLIT)   // 16
#define NT (CSPLIT / 16)   // 16-col tiles per stripe

typedef __attribute__((ext_vector_type(8))) short bf16x8;
typedef __attribute__((ext_vector_type(4))) float f32x4;

__device__ inline unsigned short f32_to_bf16_rne(float f) {
    unsigned int u = __float_as_uint(f);
    u += 0x7fffu + ((u >> 16) & 1u);   // RNE (no NaNs here)
    return (unsigned short)(u >> 16);
}
__device__ inline float bf16s_to_f32(short s) {
    unsigned int u = ((unsigned int)(unsigned short)s) << 16;
    return __uint_as_float(u);
}

// ---------------- Kernel 1: row-normalize fp32 -> bf16 (zn and znA=zn*SCALE) --
// Block 0 zeroes the scalar output (visible to k_finalize by stream order).
__global__ void k_normalize(const float* __restrict__ z_i,
                            const float* __restrict__ z_j,
                            unsigned short* __restrict__ zn,
                            unsigned short* __restrict__ znA,
                            float* __restrict__ out) {
    if (blockIdx.x == 0 && threadIdx.x == 0) out[0] = 0.f;

    int row  = blockIdx.x * 4 + (threadIdx.x >> 6);
    int lane = threadIdx.x & 63;
    const float* src = (row < B_ROWS) ? (z_i + (size_t)row * D)
                                      : (z_j + (size_t)(row - B_ROWS) * D);
    float2 v = ((const float2*)src)[lane];
    float ss = v.x * v.x + v.y * v.y;
    #pragma unroll
    for (int m = 1; m < 64; m <<= 1) ss += __shfl_xor(ss, m);
    float rinv = 1.0f / fmaxf(sqrtf(ss), 1e-8f);
    ushort2 o, oa;
    o.x  = f32_to_bf16_rne(v.x * rinv);
    o.y  = f32_to_bf16_rne(v.y * rinv);
    oa.x = f32_to_bf16_rne(v.x * rinv * SCALE);
    oa.y = f32_to_bf16_rne(v.y * rinv * SCALE);
    ((ushort2*)(zn  + (size_t)row * D))[lane] = o;
    ((ushort2*)(znA + (size_t)row * D))[lane] = oa;
}

// ---------------- Kernel 2: sim-GEMM + exp2 + partial row-sums ----------------
// grid = (32 row-groups, 16 col-stripes), block = 256 (4 waves, 64 rows each).
// A fragments (znA, pre-scaled so MFMA output is in log2 units) in registers;
// B fragments read directly from global (zn is 2 MB -> L1/L2 resident; each
// bf16x8 frag load covers exactly 16 full 64B lines). No LDS, no barriers.
// Each block writes its 256 partial row-sums to partial[stripe][row] —
// every slot written exactly once: no atomics, no zero-init needed.
__global__ __launch_bounds__(256, 2)
void k_simsum(const unsigned short* __restrict__ zn,
              const unsigned short* __restrict__ znA,
              float* __restrict__ partial) {
    const int tid  = threadIdx.x;
    const int wave = tid >> 6;
    const int lane = tid & 63;
    const int l15  = lane & 15;
    const int quad = lane >> 4;
    const int m0   = blockIdx.x * RB + wave * 64;

    // A fragments: 4 row-tiles x 4 k-blocks (A/B layouts coincide for X*X^T)
    bf16x8 A[4][4];
    #pragma unroll
    for (int rt = 0; rt < 4; ++rt)
        #pragma unroll
        for (int kb = 0; kb < 4; ++kb)
            A[rt][kb] = *(const bf16x8*)(znA + (size_t)(m0 + rt * 16 + l15) * D + kb * 32 + quad * 8);

    float rs[4][4];
    #pragma unroll
    for (int rt = 0; rt < 4; ++rt)
        #pragma unroll
        for (int j = 0; j < 4; ++j) rs[rt][j] = 0.f;

    // B fragment base for this lane: row (stripe_base + l15), byte col quad*8
    const unsigned short* bp = zn + (size_t)(blockIdx.y * CSPLIT + l15) * D + quad * 8;

    bf16x8 bc[4];
    #pragma unroll
    for (int kb = 0; kb < 4; ++kb) bc[kb] = *(const bf16x8*)(bp + kb * 32);

    for (int t = 0; t < NT; ++t) {
        bf16x8 bn[4];
        if (t + 1 < NT) {                       // prefetch next 16-col tile
            const unsigned short* np = bp + (size_t)(t + 1) * 16 * D;
            #pragma unroll
            for (int kb = 0; kb < 4; ++kb) bn[kb] = *(const bf16x8*)(np + kb * 32);
        }
        f32x4 acc[4];
        #pragma unroll
        for (int rt = 0; rt < 4; ++rt) acc[rt] = (f32x4){0.f, 0.f, 0.f, 0.f};
        #pragma unroll
        for (int kb = 0; kb < 4; ++kb)
            #pragma unroll
            for (int rt = 0; rt < 4; ++rt)
                acc[rt] = __builtin_amdgcn_mfma_f32_16x16x32_bf16(A[rt][kb], bc[kb], acc[rt], 0, 0, 0);
        #pragma unroll
        for (int rt = 0; rt < 4; ++rt)
            #pragma unroll
            for (int j = 0; j < 4; ++j)
                rs[rt][j] += __builtin_amdgcn_exp2f(acc[rt][j]);   // already log2-scaled
        if (t + 1 < NT) {
            #pragma unroll
            for (int kb = 0; kb < 4; ++kb) bc[kb] = bn[kb];
        }
    }

    // reduce partial row-sums across the 16 column lanes of each quad
    #pragma unroll
    for (int rt = 0; rt < 4; ++rt)
        #pragma unroll
        for (int j = 0; j < 4; ++j) {
            float v = rs[rt][j];
            v += __shfl_xor(v, 1);
            v += __shfl_xor(v, 2);
            v += __shfl_xor(v, 4);
            v += __shfl_xor(v, 8);
            rs[rt][j] = v;
        }
    if (l15 == 0) {
        float* dst = partial + (size_t)blockIdx.y * N_ROWS;
        #pragma unroll
        for (int rt = 0; rt < 4; ++rt)
            #pragma unroll
            for (int j = 0; j < 4; ++j)
                dst[m0 + rt * 16 + quad * 4 + j] = rs[rt][j];   // exactly-once store
    }
}

// ---------------- Kernel 3: per-row loss + mean reduce ----------------
__global__ void k_finalize(const unsigned short* __restrict__ zn,
                           const unsigned short* __restrict__ znA,
                           const float* __restrict__ partial,
                           float* __restrict__ out) {
    int i = blockIdx.x * blockDim.x + threadIdx.x;
    int p = (i + B_ROWS) & (N_ROWS - 1);

    float dsum = 0.f;
    #pragma unroll
    for (int s = 0; s < NSTRIPE; ++s)
        dsum += partial[(size_t)s * N_ROWS + i];   // coalesced across threads

    const unsigned short* ai  = znA + (size_t)i * D;   // scaled row i
    const unsigned short* bi  = zn  + (size_t)i * D;   // row i
    const unsigned short* bpp = zn  + (size_t)p * D;   // positive row
    float self_l2 = 0.f, pos_l2 = 0.f;                 // log2-scaled dots
    #pragma unroll
    for (int c = 0; c < D / 8; ++c) {
        bf16x8 a = *(const bf16x8*)(ai  + c * 8);
        bf16x8 s = *(const bf16x8*)(bi  + c * 8);
        bf16x8 q = *(const bf16x8*)(bpp + c * 8);
        #pragma unroll
        for (int j = 0; j < 8; ++j) {
            float av = bf16s_to_f32(a[j]);
            self_l2 += av * bf16s_to_f32(s[j]);
            pos_l2  += av * bf16s_to_f32(q[j]);
        }
    }
    float dnm  = dsum - __builtin_amdgcn_exp2f(self_l2);
    float loss = (__builtin_amdgcn_logf(dnm) - pos_l2) * LN2;   // ln(denom) - sim_pos

    float v = loss;
    #pragma unroll
    for (int m = 1; m < 64; m <<= 1) v += __shfl_xor(v, m);
    __shared__ float ws[4];
    int wave = threadIdx.x >> 6;
    if ((threadIdx.x & 63) == 0) ws[wave] = v;
    __syncthreads();
    if (threadIdx.x == 0) {
        float sm = ws[0] + ws[1] + ws[2] + ws[3];
        atomicAdd(out, sm * (1.0f / (float)N_ROWS));
    }
}

extern "C" void kernel_launch(void* const* d_in, const int* in_sizes, int n_in,
                              void* d_out, int out_size, void* d_ws, size_t ws_size,
                              hipStream_t stream) {
    const float* z_i = (const float*)d_in[0];
    const float* z_j = (const float*)d_in[1];
    float* out = (float*)d_out;

    char* ws = (char*)d_ws;
    unsigned short* zn      = (unsigned short*)ws;                           // 2 MB
    unsigned short* znA     = (unsigned short*)(ws + (size_t)N_ROWS * D * 2); // 2 MB
    float*          partial = (float*)(ws + (size_t)N_ROWS * D * 4);         // 16*8192*4 = 512 KB

    k_normalize<<<N_ROWS / 4, 256, 0, stream>>>(z_i, z_j, zn, znA, out);
    k_simsum<<<dim3(N_ROWS / RB, NSTRIPE), 256, 0, stream>>>(zn, znA, partial);
    k_finalize<<<N_ROWS / 256, 256, 0, stream>>>(zn, znA, partial, out);
}

// Round 6
// 96.198 us; speedup vs baseline: 1.0528x; 1.0528x over previous
//
#include <hip/hip_runtime.h>
#include <hip/hip_bf16.h>

#define B_ROWS 4096
#define N_ROWS 8192
#define D 128
#define SCALE 2.885390081777927f   // (1/temperature) * log2(e)
#define LN2 0.6931471805599453f

#define RB 256        // rows per block = 4 waves x 64 rows
#define CSPLIT 512    // columns swept per block
#define CHUNK 64      // columns staged in LDS per pass
#define NCHUNK (CSPLIT / CHUNK)

typedef __attribute__((ext_vector_type(8))) short bf16x8;
typedef __attribute__((ext_vector_type(4))) float f32x4;

__device__ inline unsigned short f32_to_bf16_rne(float f) {
    unsigned int u = __float_as_uint(f);
    u += 0x7fffu + ((u >> 16) & 1u);   // RNE (no NaNs here)
    return (unsigned short)(u >> 16);
}
__device__ inline float bf16s_to_f32(short s) {
    unsigned int u = ((unsigned int)(unsigned short)s) << 16;
    return __uint_as_float(u);
}

// ---------------- Kernel 1: row-normalize fp32 -> bf16 (zn, znA=zn*SCALE) ----
// Also zeroes denom and out (stream order makes them visible downstream).
__global__ void k_normalize(const float* __restrict__ z_i,
                            const float* __restrict__ z_j,
                            unsigned short* __restrict__ zn,
                            unsigned short* __restrict__ znA,
                            float* __restrict__ denom,
                            float* __restrict__ out) {
    if (blockIdx.x < 32) denom[blockIdx.x * 256 + threadIdx.x] = 0.f;
    if (blockIdx.x == 32 && threadIdx.x == 0) out[0] = 0.f;

    int row  = blockIdx.x * 4 + (threadIdx.x >> 6);
    int lane = threadIdx.x & 63;
    const float* src = (row < B_ROWS) ? (z_i + (size_t)row * D)
                                      : (z_j + (size_t)(row - B_ROWS) * D);
    float2 v = ((const float2*)src)[lane];
    float ss = v.x * v.x + v.y * v.y;
    #pragma unroll
    for (int m = 1; m < 64; m <<= 1) ss += __shfl_xor(ss, m);
    float rinv = 1.0f / fmaxf(sqrtf(ss), 1e-8f);
    ushort2 o, oa;
    o.x  = f32_to_bf16_rne(v.x * rinv);
    o.y  = f32_to_bf16_rne(v.y * rinv);
    oa.x = f32_to_bf16_rne(v.x * rinv * SCALE);
    oa.y = f32_to_bf16_rne(v.y * rinv * SCALE);
    ((ushort2*)(zn  + (size_t)row * D))[lane] = o;
    ((ushort2*)(znA + (size_t)row * D))[lane] = oa;
}

// ---------------- Kernel 2: fused sim-GEMM + exp2 + row-sum (R3 structure) ---
// grid = (N/RB, N/CSPLIT) = (32, 16), block = 256 (4 waves).
// Wave owns 64 rows (4 x 16-row MFMA tiles); A fragments from znA (pre-scaled
// so MFMA output is already in log2 units -> exp tail is a bare v_exp_f32).
// B chunks (64 zn rows) staged in LDS with XOR-swizzled 16B-piece layout:
//   piece(c, j) stored at index c*16 + (j ^ (c & 7)) -> conflict-free R/W.
__global__ __launch_bounds__(256, 2)
void k_simsum(const unsigned short* __restrict__ zn,
              const unsigned short* __restrict__ znA,
              float* __restrict__ denom) {
    __shared__ unsigned short sB[2 * CHUNK * 16 * 8];   // 2 x 16 KB
    const int tid  = threadIdx.x;
    const int wave = tid >> 6;
    const int lane = tid & 63;
    const int l15  = lane & 15;
    const int quad = lane >> 4;
    const int m0   = blockIdx.x * RB + wave * 64;

    // A fragments: 4 row-tiles x 4 k-blocks (A/B layouts coincide for X*X^T)
    bf16x8 A[4][4];
    #pragma unroll
    for (int rt = 0; rt < 4; ++rt)
        #pragma unroll
        for (int kb = 0; kb < 4; ++kb)
            A[rt][kb] = *(const bf16x8*)(znA + (size_t)(m0 + rt * 16 + l15) * D + kb * 32 + quad * 8);

    float rs[4][4];
    #pragma unroll
    for (int rt = 0; rt < 4; ++rt)
        #pragma unroll
        for (int j = 0; j < 4; ++j) rs[rt][j] = 0.f;

    const int c_base = blockIdx.y * CSPLIT;

    // prefetch chunk 0 into registers
    float4 st[4];
    #pragma unroll
    for (int p = 0; p < 4; ++p) {
        int i = tid + p * 256, c = i >> 4, j = i & 15;
        st[p] = *(const float4*)(zn + (size_t)(c_base + c) * D + j * 8);
    }

    for (int cb = 0; cb < NCHUNK; ++cb) {
        unsigned short* buf = sB + (cb & 1) * (CHUNK * 16 * 8);
        // commit staged registers -> LDS (swizzled)
        #pragma unroll
        for (int p = 0; p < 4; ++p) {
            int i = tid + p * 256, c = i >> 4, j = i & 15;
            int piece = c * 16 + (j ^ (c & 7));
            *(float4*)(buf + piece * 8) = st[p];
        }
        __syncthreads();   // one barrier per chunk (double-buffered)

        // prefetch next chunk while computing this one
        if (cb + 1 < NCHUNK) {
            #pragma unroll
            for (int p = 0; p < 4; ++p) {
                int i = tid + p * 256, c = i >> 4, j = i & 15;
                st[p] = *(const float4*)(zn + (size_t)(c_base + (cb + 1) * CHUNK + c) * D + j * 8);
            }
        }

        #pragma unroll
        for (int t = 0; t < 4; ++t) {           // 4 col-tiles of 16 per chunk
            bf16x8 b[4];
            #pragma unroll
            for (int kb = 0; kb < 4; ++kb) {
                int c = t * 16 + l15;
                int piece = c * 16 + ((kb * 4 + quad) ^ (c & 7));
                b[kb] = *(const bf16x8*)(buf + piece * 8);
            }
            f32x4 acc[4];
            #pragma unroll
            for (int rt = 0; rt < 4; ++rt) acc[rt] = (f32x4){0.f, 0.f, 0.f, 0.f};
            #pragma unroll
            for (int kb = 0; kb < 4; ++kb)
                #pragma unroll
                for (int rt = 0; rt < 4; ++rt)
                    acc[rt] = __builtin_amdgcn_mfma_f32_16x16x32_bf16(A[rt][kb], b[kb], acc[rt], 0, 0, 0);
            #pragma unroll
            for (int rt = 0; rt < 4; ++rt)
                #pragma unroll
                for (int j = 0; j < 4; ++j)
                    rs[rt][j] += __builtin_amdgcn_exp2f(acc[rt][j]);   // already log2-scaled
        }
    }

    // rs[rt][j]: partial row-sum for row m0+rt*16+quad*4+j over cols == l15 (mod 16)
    #pragma unroll
    for (int rt = 0; rt < 4; ++rt)
        #pragma unroll
        for (int j = 0; j < 4; ++j) {
            float v = rs[rt][j];
            v += __shfl_xor(v, 1);
            v += __shfl_xor(v, 2);
            v += __shfl_xor(v, 4);
            v += __shfl_xor(v, 8);
            rs[rt][j] = v;
        }
    if (l15 == 0) {
        #pragma unroll
        for (int rt = 0; rt < 4; ++rt)
            #pragma unroll
            for (int j = 0; j < 4; ++j)
                atomicAdd(&denom[m0 + rt * 16 + quad * 4 + j], rs[rt][j]);
    }
}

// ---------------- Kernel 3: per-row loss + mean reduce ----------------
__global__ void k_finalize(const unsigned short* __restrict__ zn,
                           const unsigned short* __restrict__ znA,
                           const float* __restrict__ denom,
                           float* __restrict__ out) {
    int i = blockIdx.x * blockDim.x + threadIdx.x;
    int p = (i + B_ROWS) & (N_ROWS - 1);
    const unsigned short* ai  = znA + (size_t)i * D;   // scaled row i
    const unsigned short* bi  = zn  + (size_t)i * D;   // row i
    const unsigned short* bpp = zn  + (size_t)p * D;   // positive row
    float self_l2 = 0.f, pos_l2 = 0.f;                 // log2-scaled dots
    #pragma unroll
    for (int c = 0; c < D / 8; ++c) {
        bf16x8 a = *(const bf16x8*)(ai  + c * 8);
        bf16x8 s = *(const bf16x8*)(bi  + c * 8);
        bf16x8 q = *(const bf16x8*)(bpp + c * 8);
        #pragma unroll
        for (int j = 0; j < 8; ++j) {
            float av = bf16s_to_f32(a[j]);
            self_l2 += av * bf16s_to_f32(s[j]);
            pos_l2  += av * bf16s_to_f32(q[j]);
        }
    }
    float dnm  = denom[i] - __builtin_amdgcn_exp2f(self_l2);
    float loss = (__builtin_amdgcn_logf(dnm) - pos_l2) * LN2;   // ln(denom) - sim_pos

    float v = loss;
    #pragma unroll
    for (int m = 1; m < 64; m <<= 1) v += __shfl_xor(v, m);
    __shared__ float ws[4];
    int wave = threadIdx.x >> 6;
    if ((threadIdx.x & 63) == 0) ws[wave] = v;
    __syncthreads();
    if (threadIdx.x == 0) {
        float sm = ws[0] + ws[1] + ws[2] + ws[3];
        atomicAdd(out, sm * (1.0f / (float)N_ROWS));
    }
}

extern "C" void kernel_launch(void* const* d_in, const int* in_sizes, int n_in,
                              void* d_out, int out_size, void* d_ws, size_t ws_size,
                              hipStream_t stream) {
    const float* z_i = (const float*)d_in[0];
    const float* z_j = (const float*)d_in[1];
    float* out = (float*)d_out;

    char* ws = (char*)d_ws;
    unsigned short* zn    = (unsigned short*)ws;                            // 2 MB
    unsigned short* znA   = (unsigned short*)(ws + (size_t)N_ROWS * D * 2); // 2 MB
    float*          denom = (float*)(ws + (size_t)N_ROWS * D * 4);          // 32 KB

    k_normalize<<<N_ROWS / 4, 256, 0, stream>>>(z_i, z_j, zn, znA, denom, out);
    k_simsum<<<dim3(N_ROWS / RB, N_ROWS / CSPLIT), 256, 0, stream>>>(zn, znA, denom);
    k_finalize<<<N_ROWS / 256, 256, 0, stream>>>(zn, znA, denom, out);
}